// Round 4
// baseline (176.843 us; speedup 1.0000x reference)
//
#include <hip/hip_runtime.h>
#include <hip/hip_bf16.h>

#define BB    262144
#define INF   256
#define HIDF  128
#define OUTF  15
#define NCAM  15
#define TM    128
#define MAXTILES (BB/TM + NCAM)   // 2063

typedef __attribute__((ext_vector_type(8))) short          bf16x8;
typedef __attribute__((ext_vector_type(4))) float          floatx4;
typedef __attribute__((ext_vector_type(4))) int            intx4;
typedef __attribute__((ext_vector_type(4))) unsigned int   uintx4;
typedef __attribute__((ext_vector_type(8))) unsigned short ushortx8;

__device__ __forceinline__ unsigned short f2bf1(float a){
  unsigned int u = __builtin_bit_cast(unsigned int, a);
  u += 0x7fffu + ((u >> 16) & 1u);          // round-to-nearest-even
  return (unsigned short)(u >> 16);
}
__device__ __forceinline__ unsigned int f2bf2(float a, float b){
  return (unsigned int)f2bf1(a) | ((unsigned int)f2bf1(b) << 16);
}

// ---------- fused prepack: W1 pack (blocks 0-239), W2 pack (240-254), zero counters (255) ----------
// W1p elem offset = ((c*8 + nf)*8 + kf)*512 + lane*8 + j
//   holds W1[c][kf*32 + (lane>>4)*8 + j][nf*16 + (lane&15)]
// W2p elem offset = (c*4 + kf)*512 + lane*8 + j ; N padded 15->16 with zeros
__global__ void k_prep(const float* __restrict__ W1, const float* __restrict__ W2,
                       unsigned short* __restrict__ W1p, unsigned short* __restrict__ W2p,
                       int* __restrict__ counts, int* __restrict__ scatterOfs){
  int bid = blockIdx.x, tid = threadIdx.x;
  if (bid < 240){
    int t = bid * 256 + tid;
    int l  = t & 63;
    int kf = (t >> 6) & 7;
    int nf = (t >> 9) & 7;
    int c  = t >> 12;
    int col = nf*16 + (l & 15);
    int k0  = kf*32 + (l >> 4)*8;
    ushortx8 v;
    #pragma unroll
    for (int j = 0; j < 8; ++j)
      v[j] = f2bf1(W1[((size_t)c*INF + k0 + j)*HIDF + col]);
    *reinterpret_cast<ushortx8*>(W1p + (size_t)t*8) = v;
  } else if (bid < 255){
    int c  = bid - 240;
    int l  = tid & 63;
    int kf = tid >> 6;            // 0..3
    int col = l & 15;
    int k0  = kf*32 + (l >> 4)*8;
    ushortx8 v;
    #pragma unroll
    for (int j = 0; j < 8; ++j){
      float f = (col < OUTF) ? W2[((size_t)c*HIDF + k0 + j)*OUTF + col] : 0.0f;
      v[j] = f2bf1(f);
    }
    *reinterpret_cast<ushortx8*>(W2p + ((size_t)(c*4 + kf)*64 + l)*8) = v;
  } else {
    if (tid < 16) counts[tid] = 0;
    else if (tid < 32) scatterOfs[tid - 16] = 0;
  }
}

// ---------- histogram ----------
__global__ void k_hist(const int* __restrict__ cam, int* __restrict__ counts){
  __shared__ int lc[NCAM];
  int t = threadIdx.x;
  if (t < NCAM) lc[t] = 0;
  __syncthreads();
  intx4 v = *reinterpret_cast<const intx4*>(cam + (size_t)(blockIdx.x*256 + t)*4);
  atomicAdd(&lc[v[0]], 1); atomicAdd(&lc[v[1]], 1);
  atomicAdd(&lc[v[2]], 1); atomicAdd(&lc[v[3]], 1);
  __syncthreads();
  if (t < NCAM && lc[t]) atomicAdd(&counts[t], lc[t]);
}

// ---------- scatter (local scan from counts; atomic cursor from 0) ----------
__global__ void k_scatter(const int* __restrict__ cam, const int* __restrict__ counts,
                          int* __restrict__ scatterOfs, int* __restrict__ idx){
  __shared__ int lc[NCAM];
  __shared__ int loff[NCAM];
  __shared__ int base[NCAM];
  int t = threadIdx.x;
  if (t < NCAM) lc[t] = 0;
  __syncthreads();
  int start = blockIdx.x * 4096;
  int camr[16], lpos[16];
  #pragma unroll
  for (int j = 0; j < 16; ++j){
    int i = start + j*256 + t;
    camr[j] = cam[i];
    lpos[j] = atomicAdd(&lc[camr[j]], 1);
  }
  __syncthreads();
  if (t == 0){
    int s = 0;
    #pragma unroll
    for (int c = 0; c < NCAM; ++c){ loff[c] = s; s += counts[c]; }
  }
  __syncthreads();
  if (t < NCAM) base[t] = loff[t] + atomicAdd(&scatterOfs[t], lc[t]);
  __syncthreads();
  #pragma unroll
  for (int j = 0; j < 16; ++j)
    idx[base[camr[j]] + lpos[j]] = start + j*256 + t;
}

// ---------- main fused MLP (R2 structure: gather interleaved with MFMA) ----------
__global__ __launch_bounds__(256, 4) void k_mlp(
    const float* __restrict__ x, const int* __restrict__ idx,
    const int* __restrict__ counts,
    const unsigned short* __restrict__ W1p, const unsigned short* __restrict__ W2p,
    const float* __restrict__ b1, const float* __restrict__ b2,
    float* __restrict__ out)
{
  __shared__ int sidx[TM];
  __shared__ unsigned short hbuf[TM][HIDF];   // 32 KB, XOR-swizzled columns

  // map blockIdx -> (camera, tile) from counts only
  int bid = blockIdx.x;
  int c = -1, segStart = 0, rowStart = 0, rows = 0;
  {
    int cum = 0, rcum = 0;
    #pragma unroll 1
    for (int cc = 0; cc < NCAM; ++cc){
      int n  = counts[cc];
      int nt = (n + TM - 1) / TM;
      if (c < 0 && bid < cum + nt){
        c = cc;
        rowStart = (bid - cum) * TM;
        segStart = rcum;
        rows = n - rowStart; if (rows > TM) rows = TM;
      }
      cum += nt; rcum += n;
    }
  }
  if (c < 0) return;

  int t = threadIdx.x;
  if (t < TM){
    int r = (t < rows) ? t : (rows - 1);
    sidx[t] = idx[segStart + rowStart + r];
  }
  __syncthreads();

  int wave = t >> 6, lane = t & 63;
  int wr  = wave * 32;                 // each wave owns 32 rows, all 128 cols
  int l15 = lane & 15, lk = lane >> 4;

  const float* aptr0 = x + (size_t)sidx[wr + l15]      * INF + lk*8;
  const float* aptr1 = x + (size_t)sidx[wr + 16 + l15] * INF + lk*8;

  const unsigned short* bbase = W1p + (size_t)c*32768 + lane*8;

  floatx4 acc[2][8];
  #pragma unroll
  for (int i = 0; i < 2; ++i)
    #pragma unroll
    for (int j = 0; j < 8; ++j) acc[i][j] = (floatx4)0.0f;

  #pragma unroll
  for (int kf = 0; kf < 8; ++kf){
    // A gathers (HBM): 4 x 16B per lane-pairset; full 128B cachelines per row
    floatx4 a00 = *reinterpret_cast<const floatx4*>(aptr0 + kf*32);
    floatx4 a01 = *reinterpret_cast<const floatx4*>(aptr0 + kf*32 + 4);
    floatx4 a10 = *reinterpret_cast<const floatx4*>(aptr1 + kf*32);
    floatx4 a11 = *reinterpret_cast<const floatx4*>(aptr1 + kf*32 + 4);
    // B fragments (L2-resident packed weights)
    bf16x8 bf[8];
    #pragma unroll
    for (int nf = 0; nf < 8; ++nf)
      bf[nf] = *reinterpret_cast<const bf16x8*>(bbase + nf*4096 + kf*512);
    uintx4 u0, u1;
    u0[0] = f2bf2(a00[0], a00[1]); u0[1] = f2bf2(a00[2], a00[3]);
    u0[2] = f2bf2(a01[0], a01[1]); u0[3] = f2bf2(a01[2], a01[3]);
    u1[0] = f2bf2(a10[0], a10[1]); u1[1] = f2bf2(a10[2], a10[3]);
    u1[2] = f2bf2(a11[0], a11[1]); u1[3] = f2bf2(a11[2], a11[3]);
    bf16x8 af0 = __builtin_bit_cast(bf16x8, u0);
    bf16x8 af1 = __builtin_bit_cast(bf16x8, u1);
    #pragma unroll
    for (int nf = 0; nf < 8; ++nf)
      acc[0][nf] = __builtin_amdgcn_mfma_f32_16x16x32_bf16(af0, bf[nf], acc[0][nf], 0, 0, 0);
    #pragma unroll
    for (int nf = 0; nf < 8; ++nf)
      acc[1][nf] = __builtin_amdgcn_mfma_f32_16x16x32_bf16(af1, bf[nf], acc[1][nf], 0, 0, 0);
  }

  // layer-1 epilogue: bias + relu -> swizzled LDS (bf16)
  #pragma unroll
  for (int nf = 0; nf < 8; ++nf){
    int col = nf*16 + l15;
    float bias = b1[c*HIDF + col];
    #pragma unroll
    for (int mf = 0; mf < 2; ++mf){
      #pragma unroll
      for (int j = 0; j < 4; ++j){
        int row = wr + mf*16 + lk*4 + j;
        float h = fmaxf(acc[mf][nf][j] + bias, 0.0f);
        int cb = (col*2) ^ ((row & 7) << 4);
        *reinterpret_cast<unsigned short*>(
            reinterpret_cast<char*>(&hbuf[row][0]) + cb) = f2bf1(h);
      }
    }
  }
  __syncthreads();

  // layer 2: [32 rows x 128] x [128 x 16(pad)]
  floatx4 acc2[2];
  acc2[0] = (floatx4)0.0f; acc2[1] = (floatx4)0.0f;
  const unsigned short* wb = W2p + (size_t)c*2048 + lane*8;
  #pragma unroll
  for (int kf = 0; kf < 4; ++kf){
    bf16x8 wv = *reinterpret_cast<const bf16x8*>(wb + kf*512);
    #pragma unroll
    for (int mf = 0; mf < 2; ++mf){
      int row = wr + mf*16 + l15;
      int cb = ((kf*64 + lk*16)) ^ ((row & 7) << 4);
      bf16x8 av = *reinterpret_cast<const bf16x8*>(
          reinterpret_cast<char*>(&hbuf[row][0]) + cb);
      acc2[mf] = __builtin_amdgcn_mfma_f32_16x16x32_bf16(av, wv, acc2[mf], 0, 0, 0);
    }
  }

  int col = l15;
  if (col < OUTF){
    float bias2 = b2[c*OUTF + col];
    #pragma unroll
    for (int mf = 0; mf < 2; ++mf){
      #pragma unroll
      for (int j = 0; j < 4; ++j){
        int r = wr + mf*16 + lk*4 + j;
        if (r < rows)
          out[(size_t)sidx[r]*OUTF + col] = acc2[mf][j] + bias2;
      }
    }
  }
}

extern "C" void kernel_launch(void* const* d_in, const int* in_sizes, int n_in,
                              void* d_out, int out_size, void* d_ws, size_t ws_size,
                              hipStream_t stream) {
  const float* x  = (const float*)d_in[0];
  const int*   cam= (const int*)d_in[1];
  const float* W1 = (const float*)d_in[2];
  const float* b1 = (const float*)d_in[3];
  const float* W2 = (const float*)d_in[4];
  const float* b2 = (const float*)d_in[5];
  float* out = (float*)d_out;

  char* ws = (char*)d_ws;
  int* counts     = (int*)(ws);          // 16 ints
  int* scatterOfs = (int*)(ws + 64);     // 16 ints
  int* idx        = (int*)(ws + 256);    // BB ints (1 MB)
  unsigned short* W1p = (unsigned short*)(ws + 256 + (size_t)BB*4);       // 983040 B
  unsigned short* W2p = W1p + (size_t)NCAM*8*8*64*8;                      // 61440 B

  hipLaunchKernelGGL(k_prep,    dim3(256),     dim3(256), 0, stream, W1, W2, W1p, W2p, counts, scatterOfs);
  hipLaunchKernelGGL(k_hist,    dim3(256),     dim3(256), 0, stream, cam, counts);
  hipLaunchKernelGGL(k_scatter, dim3(BB/4096), dim3(256), 0, stream, cam, counts, scatterOfs, idx);
  hipLaunchKernelGGL(k_mlp,     dim3(MAXTILES),dim3(256), 0, stream,
                     x, idx, counts, W1p, W2p, b1, b2, out);
}

// Round 5
// 97.866 us; speedup vs baseline: 1.8070x; 1.8070x over previous
//
#include <hip/hip_runtime.h>
#include <hip/hip_bf16.h>

#define BB    262144
#define INF   256
#define HIDF  128
#define OUTF  15
#define NCAM  15
#define TM    128
#define MAXTILES (BB/TM + NCAM)   // 2063

typedef __attribute__((ext_vector_type(8))) short          bf16x8;
typedef __attribute__((ext_vector_type(4))) float          floatx4;
typedef __attribute__((ext_vector_type(4))) int            intx4;
typedef __attribute__((ext_vector_type(4))) unsigned int   uintx4;
typedef __attribute__((ext_vector_type(8))) unsigned short ushortx8;

__device__ __forceinline__ unsigned short f2bf1(float a){
  unsigned int u = __builtin_bit_cast(unsigned int, a);
  u += 0x7fffu + ((u >> 16) & 1u);          // round-to-nearest-even
  return (unsigned short)(u >> 16);
}
__device__ __forceinline__ unsigned int f2bf2(float a, float b){
  return (unsigned int)f2bf1(a) | ((unsigned int)f2bf1(b) << 16);
}

// ---------- fused prepack: W1 pack (blocks 0-239), W2 pack (240-254), zero counters (255) ----------
__global__ void k_prep(const float* __restrict__ W1, const float* __restrict__ W2,
                       unsigned short* __restrict__ W1p, unsigned short* __restrict__ W2p,
                       int* __restrict__ counts, int* __restrict__ scatterOfs){
  int bid = blockIdx.x, tid = threadIdx.x;
  if (bid < 240){
    int t = bid * 256 + tid;
    int l  = t & 63;
    int kf = (t >> 6) & 7;
    int nf = (t >> 9) & 7;
    int c  = t >> 12;
    int col = nf*16 + (l & 15);
    int k0  = kf*32 + (l >> 4)*8;
    ushortx8 v;
    #pragma unroll
    for (int j = 0; j < 8; ++j)
      v[j] = f2bf1(W1[((size_t)c*INF + k0 + j)*HIDF + col]);
    *reinterpret_cast<ushortx8*>(W1p + (size_t)t*8) = v;
  } else if (bid < 255){
    int c  = bid - 240;
    int l  = tid & 63;
    int kf = tid >> 6;            // 0..3
    int col = l & 15;
    int k0  = kf*32 + (l >> 4)*8;
    ushortx8 v;
    #pragma unroll
    for (int j = 0; j < 8; ++j){
      float f = (col < OUTF) ? W2[((size_t)c*HIDF + k0 + j)*OUTF + col] : 0.0f;
      v[j] = f2bf1(f);
    }
    *reinterpret_cast<ushortx8*>(W2p + ((size_t)(c*4 + kf)*64 + l)*8) = v;
  } else {
    if (tid < 16) counts[tid] = 0;
    else if (tid < 32) scatterOfs[tid - 16] = 0;
  }
}

// ---------- histogram ----------
__global__ void k_hist(const int* __restrict__ cam, int* __restrict__ counts){
  __shared__ int lc[NCAM];
  int t = threadIdx.x;
  if (t < NCAM) lc[t] = 0;
  __syncthreads();
  intx4 v = *reinterpret_cast<const intx4*>(cam + (size_t)(blockIdx.x*256 + t)*4);
  atomicAdd(&lc[v[0]], 1); atomicAdd(&lc[v[1]], 1);
  atomicAdd(&lc[v[2]], 1); atomicAdd(&lc[v[3]], 1);
  __syncthreads();
  if (t < NCAM && lc[t]) atomicAdd(&counts[t], lc[t]);
}

// ---------- scatter ----------
__global__ void k_scatter(const int* __restrict__ cam, const int* __restrict__ counts,
                          int* __restrict__ scatterOfs, int* __restrict__ idx){
  __shared__ int lc[NCAM];
  __shared__ int loff[NCAM];
  __shared__ int base[NCAM];
  int t = threadIdx.x;
  if (t < NCAM) lc[t] = 0;
  __syncthreads();
  int start = blockIdx.x * 4096;
  int camr[16], lpos[16];
  #pragma unroll
  for (int j = 0; j < 16; ++j){
    int i = start + j*256 + t;
    camr[j] = cam[i];
    lpos[j] = atomicAdd(&lc[camr[j]], 1);
  }
  __syncthreads();
  if (t == 0){
    int s = 0;
    #pragma unroll
    for (int c = 0; c < NCAM; ++c){ loff[c] = s; s += counts[c]; }
  }
  __syncthreads();
  if (t < NCAM) base[t] = loff[t] + atomicAdd(&scatterOfs[t], lc[t]);
  __syncthreads();
  #pragma unroll
  for (int j = 0; j < 16; ++j)
    idx[base[camr[j]] + lpos[j]] = start + j*256 + t;
}

// ---------- main fused MLP: deep register-pipelined gather + MFMA ----------
__global__ __launch_bounds__(256, 2) void k_mlp(
    const float* __restrict__ x, const int* __restrict__ idx,
    const int* __restrict__ counts,
    const unsigned short* __restrict__ W1p, const unsigned short* __restrict__ W2p,
    const float* __restrict__ b1, const float* __restrict__ b2,
    float* __restrict__ out)
{
  __shared__ int sidx[TM];
  __shared__ unsigned short hbuf[TM][HIDF];   // 32 KB, XOR-swizzled columns

  int bid = blockIdx.x;
  int c = -1, segStart = 0, rowStart = 0, rows = 0;
  {
    int cum = 0, rcum = 0;
    #pragma unroll 1
    for (int cc = 0; cc < NCAM; ++cc){
      int n  = counts[cc];
      int nt = (n + TM - 1) / TM;
      if (c < 0 && bid < cum + nt){
        c = cc;
        rowStart = (bid - cum) * TM;
        segStart = rcum;
        rows = n - rowStart; if (rows > TM) rows = TM;
      }
      cum += nt; rcum += n;
    }
  }
  if (c < 0) return;

  int t = threadIdx.x;
  if (t < TM){
    int r = (t < rows) ? t : (rows - 1);
    sidx[t] = idx[segStart + rowStart + r];
  }
  __syncthreads();

  int wave = t >> 6, lane = t & 63;
  int wr  = wave * 32;
  int l15 = lane & 15, lk = lane >> 4;

  const float* ap0 = x + (size_t)sidx[wr + l15]      * INF + lk*8;
  const float* ap1 = x + (size_t)sidx[wr + 16 + l15] * INF + lk*8;
  const unsigned short* bbase = W1p + (size_t)c*32768 + lane*8;

  floatx4 acc[2][8];
  #pragma unroll
  for (int i = 0; i < 2; ++i)
    #pragma unroll
    for (int j = 0; j < 8; ++j) acc[i][j] = (floatx4)0.0f;

  // pipeline registers: A 3-deep, B 2-deep
  floatx4 a[3][4];      // [slot][mf0-lo, mf0-hi, mf1-lo, mf1-hi]
  bf16x8  bfr[2][8];

  #pragma unroll
  for (int s = 0; s < 3; ++s){
    a[s][0] = *reinterpret_cast<const floatx4*>(ap0 + s*32);
    a[s][1] = *reinterpret_cast<const floatx4*>(ap0 + s*32 + 4);
    a[s][2] = *reinterpret_cast<const floatx4*>(ap1 + s*32);
    a[s][3] = *reinterpret_cast<const floatx4*>(ap1 + s*32 + 4);
  }
  #pragma unroll
  for (int nf = 0; nf < 8; ++nf)
    bfr[0][nf] = *reinterpret_cast<const bf16x8*>(bbase + nf*4096);

  #pragma unroll
  for (int kf = 0; kf < 8; ++kf){
    const int cur  = kf % 3;        // compile-time after unroll
    const int bcur = kf & 1;
    // B prefetch (kf+1) — issued BEFORE the A prefetch so counted vmcnt
    // waits for B leave the deeper A gathers in flight
    if (kf < 7){
      #pragma unroll
      for (int nf = 0; nf < 8; ++nf)
        bfr[bcur^1][nf] = *reinterpret_cast<const bf16x8*>(bbase + nf*4096 + (kf+1)*512);
    }
    // convert current A slot to bf16 fragments
    uintx4 u0, u1;
    u0[0] = f2bf2(a[cur][0][0], a[cur][0][1]); u0[1] = f2bf2(a[cur][0][2], a[cur][0][3]);
    u0[2] = f2bf2(a[cur][1][0], a[cur][1][1]); u0[3] = f2bf2(a[cur][1][2], a[cur][1][3]);
    u1[0] = f2bf2(a[cur][2][0], a[cur][2][1]); u1[1] = f2bf2(a[cur][2][2], a[cur][2][3]);
    u1[2] = f2bf2(a[cur][3][0], a[cur][3][1]); u1[3] = f2bf2(a[cur][3][2], a[cur][3][3]);
    bf16x8 af0 = __builtin_bit_cast(bf16x8, u0);
    bf16x8 af1 = __builtin_bit_cast(bf16x8, u1);
    // A prefetch (kf+3) into the slot just consumed
    if (kf < 5){
      a[cur][0] = *reinterpret_cast<const floatx4*>(ap0 + (kf+3)*32);
      a[cur][1] = *reinterpret_cast<const floatx4*>(ap0 + (kf+3)*32 + 4);
      a[cur][2] = *reinterpret_cast<const floatx4*>(ap1 + (kf+3)*32);
      a[cur][3] = *reinterpret_cast<const floatx4*>(ap1 + (kf+3)*32 + 4);
    }
    #pragma unroll
    for (int nf = 0; nf < 8; ++nf)
      acc[0][nf] = __builtin_amdgcn_mfma_f32_16x16x32_bf16(af0, bfr[bcur][nf], acc[0][nf], 0, 0, 0);
    #pragma unroll
    for (int nf = 0; nf < 8; ++nf)
      acc[1][nf] = __builtin_amdgcn_mfma_f32_16x16x32_bf16(af1, bfr[bcur][nf], acc[1][nf], 0, 0, 0);
  }

  // layer-1 epilogue: bias + relu -> swizzled LDS (bf16)
  #pragma unroll
  for (int nf = 0; nf < 8; ++nf){
    int col = nf*16 + l15;
    float bias = b1[c*HIDF + col];
    #pragma unroll
    for (int mf = 0; mf < 2; ++mf){
      #pragma unroll
      for (int j = 0; j < 4; ++j){
        int row = wr + mf*16 + lk*4 + j;
        float h = fmaxf(acc[mf][nf][j] + bias, 0.0f);
        int cb = (col*2) ^ ((row & 7) << 4);
        *reinterpret_cast<unsigned short*>(
            reinterpret_cast<char*>(&hbuf[row][0]) + cb) = f2bf1(h);
      }
    }
  }
  __syncthreads();

  // layer 2: [32 rows x 128] x [128 x 16(pad)]
  floatx4 acc2[2];
  acc2[0] = (floatx4)0.0f; acc2[1] = (floatx4)0.0f;
  const unsigned short* wb = W2p + (size_t)c*2048 + lane*8;
  #pragma unroll
  for (int kf = 0; kf < 4; ++kf){
    bf16x8 wv = *reinterpret_cast<const bf16x8*>(wb + kf*512);
    #pragma unroll
    for (int mf = 0; mf < 2; ++mf){
      int row = wr + mf*16 + l15;
      int cb = (kf*64 + lk*16) ^ ((row & 7) << 4);
      bf16x8 av = *reinterpret_cast<const bf16x8*>(
          reinterpret_cast<char*>(&hbuf[row][0]) + cb);
      acc2[mf] = __builtin_amdgcn_mfma_f32_16x16x32_bf16(av, wv, acc2[mf], 0, 0, 0);
    }
  }

  int col = l15;
  if (col < OUTF){
    float bias2 = b2[c*OUTF + col];
    #pragma unroll
    for (int mf = 0; mf < 2; ++mf){
      #pragma unroll
      for (int j = 0; j < 4; ++j){
        int r = wr + mf*16 + lk*4 + j;
        if (r < rows)
          out[(size_t)sidx[r]*OUTF + col] = acc2[mf][j] + bias2;
      }
    }
  }
}

extern "C" void kernel_launch(void* const* d_in, const int* in_sizes, int n_in,
                              void* d_out, int out_size, void* d_ws, size_t ws_size,
                              hipStream_t stream) {
  const float* x  = (const float*)d_in[0];
  const int*   cam= (const int*)d_in[1];
  const float* W1 = (const float*)d_in[2];
  const float* b1 = (const float*)d_in[3];
  const float* W2 = (const float*)d_in[4];
  const float* b2 = (const float*)d_in[5];
  float* out = (float*)d_out;

  char* ws = (char*)d_ws;
  int* counts     = (int*)(ws);          // 16 ints
  int* scatterOfs = (int*)(ws + 64);     // 16 ints
  int* idx        = (int*)(ws + 256);    // BB ints (1 MB)
  unsigned short* W1p = (unsigned short*)(ws + 256 + (size_t)BB*4);       // 983040 B
  unsigned short* W2p = W1p + (size_t)NCAM*8*8*64*8;                      // 61440 B

  hipLaunchKernelGGL(k_prep,    dim3(256),     dim3(256), 0, stream, W1, W2, W1p, W2p, counts, scatterOfs);
  hipLaunchKernelGGL(k_hist,    dim3(256),     dim3(256), 0, stream, cam, counts);
  hipLaunchKernelGGL(k_scatter, dim3(BB/4096), dim3(256), 0, stream, cam, counts, scatterOfs, idx);
  hipLaunchKernelGGL(k_mlp,     dim3(MAXTILES),dim3(256), 0, stream,
                     x, idx, counts, W1p, W2p, b1, b2, out);
}